// Round 7
// baseline (279.109 us; speedup 1.0000x reference)
//
#include <hip/hip_runtime.h>
#include <hip/hip_bf16.h>

#define M_DIM 16384
#define N_DIM 1000
#define N_PAD 1024
#define K_DIM 2048
#define INV_F (1.0f / 2048.0f)

#define BM 256
#define BN 256
#define BK 64
#define NT (K_DIM / BK)          // 32 K-tiles
#define NI (NT / 2)              // 16 iterations, 2 tiles each
#define A_E (BM * BK)            // 16384 elems = 32 KB per matrix per buf
#define SLOT_E (2 * A_E)         // A+B per buf = 64 KB

typedef __bf16 bf16v8 __attribute__((ext_vector_type(8)));
typedef float  f32v4  __attribute__((ext_vector_type(4)));
typedef unsigned int u32;

__device__ __forceinline__ void gload_lds16(const void* g, void* l) {
  __builtin_amdgcn_global_load_lds(
      (const __attribute__((address_space(1))) u32*)g,
      (__attribute__((address_space(3))) u32*)l, 16, 0, 0);
}

// ---------------------------------------------------------------------------
// fp32 row -> bf16 row + fp32 sum-of-squares. One wave per row, no LDS/syncs.
// Rows >= nvalid zeroed (w padding; d_ws is re-poisoned 0xAA every launch).
// ---------------------------------------------------------------------------
__global__ __launch_bounds__(256) void cvt_rows(
    const float* __restrict__ src, __bf16* __restrict__ dst,
    float* __restrict__ sq, int nvalid)
{
  const int row  = blockIdx.x * 4 + (threadIdx.x >> 6);
  const int lane = threadIdx.x & 63;
  const float4* sr = (const float4*)(src + (size_t)row * K_DIM);
  bf16v8* dr = (bf16v8*)(dst + (size_t)row * K_DIM);
  float s = 0.0f;
  if (row < nvalid) {
    #pragma unroll
    for (int i = 0; i < 4; ++i) {
      float4 a = sr[2 * lane + i * 128];
      float4 b = sr[2 * lane + 1 + i * 128];
      s += a.x*a.x + a.y*a.y + a.z*a.z + a.w*a.w
         + b.x*b.x + b.y*b.y + b.z*b.z + b.w*b.w;
      bf16v8 o;
      o[0]=(__bf16)a.x; o[1]=(__bf16)a.y; o[2]=(__bf16)a.z; o[3]=(__bf16)a.w;
      o[4]=(__bf16)b.x; o[5]=(__bf16)b.y; o[6]=(__bf16)b.z; o[7]=(__bf16)b.w;
      dr[lane + i * 64] = o;
    }
  } else {
    bf16v8 z;
    #pragma unroll
    for (int k = 0; k < 8; ++k) z[k] = (__bf16)0.0f;
    #pragma unroll
    for (int i = 0; i < 4; ++i) dr[lane + i * 64] = z;
  }
  #pragma unroll
  for (int off = 32; off > 0; off >>= 1) s += __shfl_down(s, off, 64);
  if (lane == 0) sq[row] = s;
}

// ---------------------------------------------------------------------------
// 256x256 bf16 MFMA GEMM — m201 8-phase template port. BK=64, 2 fixed-parity
// LDS buffers (even tile -> buf0, odd -> buf1; 128 KB), 8 waves (2M x 4N).
// Per iteration: 2 K-tiles, 8 phases, each phase =
//   { ds_reads (0/4/8/12 b128) ; stage 1 half-tile (2 gloads) ;
//     [vmcnt(6) at ph4/ph8 ONLY] ; s_barrier ; lgkmcnt(0)+sched_barrier ;
//     setprio(1) 16 MFMA setprio(0) ; s_barrier }
// Stage schedule: ph1 AH2(O) | ph2 AH1(E+2) | ph3 BH1(E+2) | ph4 BH2(E+2) |
//                 ph5 AH2(E+2) | ph6 AH1(O+2) | ph7 BH1(O+2) | ph8 BH2(O+2)
// Half-tiles consumption-aligned (proven r6): A-H1 rows {0-63,128-191};
// B-H1 rows {0-31,64-95,128-159,192-223}. vmcnt(6) = 3 half-tiles in flight:
// at ph4 it guarantees AH2(O)[ph1] + prev O-halves landed (-> ph5-7 reads);
// at ph8 it guarantees all 4 E+2 halves landed (-> next ph1-3 reads). Endgame:
// ph4 uses vmcnt(0) when E+2 >= NT (covers last AH2(O)). WAR: each region
// overwritten >= 1 post-MFMA barrier after its last reads drained (lgkm0).
// LDS swizzle (proven r5/r6): chunk q of row r at slot q^(r&7); staging dest
// linear per wave, global source inverse-permuted (coalescing kept).
// Epilogue fuses out = (2*acc - x2[r] - w2[c]) / F, guard c < 1000.
// ---------------------------------------------------------------------------
__global__ __launch_bounds__(512, 2) void gemm_ep(
    const __bf16* __restrict__ A, const __bf16* __restrict__ B,
    const float* __restrict__ x2, const float* __restrict__ w2,
    float* __restrict__ out)
{
  __shared__ __bf16 lds[2 * SLOT_E];   // 128 KB

  // T1: bijective XCD swizzle (256 blocks % 8 == 0): each XCD owns 8 A-panels.
  const int bid = blockIdx.x;
  const int swz = (bid & 7) * 32 + (bid >> 3);
  const int bm = swz >> 2;          // 64 row tiles
  const int bn = swz & 3;           // 4 col tiles, fastest (A-panel reuse)
  const int brow = bm * BM;
  const int bcol = bn * BN;

  const int tid  = threadIdx.x;
  const int lane = tid & 63;
  const int wid  = tid >> 6;
  const int wm   = wid >> 2;        // 0..1
  const int wn   = wid & 3;         // 0..3

  // ---- staging geometry: per half-tile, 2 loads/thread (l=0,1) ----
  const __bf16* srcA[4]; const __bf16* srcB[4];
  int dstA[4], dstB[4];
  #pragma unroll
  for (int h = 0; h < 2; ++h)
    #pragma unroll
    for (int l = 0; l < 2; ++l) {
      const int i = l * 512 + tid;
      const int p = i >> 3;         // 0..127 within half-tile
      const int slot = i & 7;
      const int rowA = ((p < 64) ? p : p + 64) + h * 64;   // H1:{0-63,128-191}
      srcA[h*2+l] = A + (size_t)(brow + rowA) * K_DIM + (slot ^ (rowA & 7)) * 8;
      dstA[h*2+l] = rowA * 64 + slot * 8;
      const int rowB = ((p >> 5) * 64 + (p & 31)) + h * 32; // H1: first 32 of each 64
      srcB[h*2+l] = B + (size_t)(bcol + rowB) * K_DIM + (slot ^ (rowB & 7)) * 8;
      dstB[h*2+l] = A_E + rowB * 64 + slot * 8;
    }

#define STAGE_A(h, kt, nb) do {                                          \
    gload_lds16(srcA[(h)*2+0] + (size_t)(kt) * BK, (nb) + dstA[(h)*2+0]);\
    gload_lds16(srcA[(h)*2+1] + (size_t)(kt) * BK, (nb) + dstA[(h)*2+1]);\
  } while (0)
#define STAGE_B(h, kt, nb) do {                                          \
    gload_lds16(srcB[(h)*2+0] + (size_t)(kt) * BK, (nb) + dstB[(h)*2+0]);\
    gload_lds16(srcB[(h)*2+1] + (size_t)(kt) * BK, (nb) + dstB[(h)*2+1]);\
  } while (0)

  // ---- fragment read offsets (swizzled, per-lane constant) ----
  const int lr = lane & 15;
  const int g  = lane >> 4;
  const int lkx[2] = { ((0 + g) ^ (lr & 7)) * 8, ((4 + g) ^ (lr & 7)) * 8 };
  const int aBase = (wm * 128 + lr) * 64;          // + m*1024 + lkx[s]
  const int bBase = A_E + (wn * 64 + lr) * 64;     // + n*1024 + lkx[s]

  f32v4 acc[8][4];
  #pragma unroll
  for (int m = 0; m < 8; ++m)
    #pragma unroll
    for (int n = 0; n < 4; ++n)
      acc[m][n] = (f32v4){0.f, 0.f, 0.f, 0.f};

  bf16v8 a[4][2], b[4][2];

#define DS_A(buf, mb) do {                                               \
    _Pragma("unroll") for (int m = 0; m < 4; ++m)                        \
      _Pragma("unroll") for (int s = 0; s < 2; ++s)                      \
        a[m][s] = *(const bf16v8*)((buf) + aBase + ((mb)+m)*1024 + lkx[s]); \
  } while (0)
#define DS_B(buf, nb) do {                                               \
    _Pragma("unroll") for (int n = 0; n < 2; ++n)                        \
      _Pragma("unroll") for (int s = 0; s < 2; ++s)                      \
        b[(nb)+n][s] = *(const bf16v8*)((buf) + bBase + ((nb)+n)*1024 + lkx[s]); \
  } while (0)
#define MFMA_Q(mb, nb) do {                                              \
    __builtin_amdgcn_s_setprio(1);                                       \
    _Pragma("unroll") for (int m = 0; m < 4; ++m)                        \
      _Pragma("unroll") for (int n = 0; n < 2; ++n) {                    \
        acc[(mb)+m][(nb)+n] = __builtin_amdgcn_mfma_f32_16x16x32_bf16(   \
            a[m][0], b[(nb)+n][0], acc[(mb)+m][(nb)+n], 0, 0, 0);        \
        acc[(mb)+m][(nb)+n] = __builtin_amdgcn_mfma_f32_16x16x32_bf16(   \
            a[m][1], b[(nb)+n][1], acc[(mb)+m][(nb)+n], 0, 0, 0);        \
      }                                                                  \
    __builtin_amdgcn_s_setprio(0);                                       \
  } while (0)
#define SB   __builtin_amdgcn_sched_barrier(0)
#define BARR __builtin_amdgcn_s_barrier()
#define LGKM0 asm volatile("s_waitcnt lgkmcnt(0)" ::: "memory")
#define VM6  asm volatile("s_waitcnt vmcnt(6)" ::: "memory")
#define VM0  asm volatile("s_waitcnt vmcnt(0)" ::: "memory")

  const __bf16* c0 = (const __bf16*)lds;           // even-tile buffer
  const __bf16* c1 = (const __bf16*)lds + SLOT_E;  // odd-tile buffer
  __bf16* w0 = (__bf16*)lds;
  __bf16* w1 = (__bf16*)lds + SLOT_E;

  // ---- prologue: 7 halves (tile0 full, tile1 minus AH2); tile0 landed ----
  STAGE_A(0, 0, w0); STAGE_B(0, 0, w0); STAGE_B(1, 0, w0); STAGE_A(1, 0, w0);
  STAGE_A(0, 1, w1); STAGE_B(0, 1, w1); STAGE_B(1, 1, w1);
  VM6; BARR; SB;

  #pragma unroll 1
  for (int i = 0; i < NI; ++i) {
    const int O = 2 * i + 1, E2 = 2 * i + 2, O2 = 2 * i + 3;
    const bool mE = (E2 < NT), mO = (O2 < NT);

    // ph1: E q(m0-3,n0-1); stage AH2(O)
    DS_A(c0, 0); DS_B(c0, 0);
    STAGE_A(1, O, w1);
    SB; BARR; LGKM0; SB; MFMA_Q(0, 0); BARR;

    // ph2: E q(m0-3,n2-3); stage AH1(E2)
    DS_B(c0, 2);
    if (mE) STAGE_A(0, E2, w0);
    SB; BARR; LGKM0; SB; MFMA_Q(0, 2); BARR;

    // ph3: E q(m4-7,n0-1); stage BH1(E2)
    DS_A(c0, 4);
    if (mE) STAGE_B(0, E2, w0);
    SB; BARR; LGKM0; SB; MFMA_Q(4, 0); BARR;

    // ph4: E q(m4-7,n2-3); stage BH2(E2); vmcnt (once per tile)
    if (mE) STAGE_B(1, E2, w0);
    SB; if (mE) { VM6; } else { VM0; }
    BARR; SB; MFMA_Q(4, 2); BARR;

    // ph5: O q(m0-3,n0-1); stage AH2(E2)
    DS_A(c1, 0); DS_B(c1, 0);
    if (mE) STAGE_A(1, E2, w0);
    SB; BARR; LGKM0; SB; MFMA_Q(0, 0); BARR;

    // ph6: O q(m0-3,n2-3); stage AH1(O2)
    DS_B(c1, 2);
    if (mO) STAGE_A(0, O2, w1);
    SB; BARR; LGKM0; SB; MFMA_Q(0, 2); BARR;

    // ph7: O q(m4-7,n0-1); stage BH1(O2)
    DS_A(c1, 4);
    if (mO) STAGE_B(0, O2, w1);
    SB; BARR; LGKM0; SB; MFMA_Q(4, 0); BARR;

    // ph8: O q(m4-7,n2-3); stage BH2(O2); vmcnt (once per tile)
    if (mO) STAGE_B(1, O2, w1);
    SB; if (mO) { VM6; } else { VM0; }
    BARR; SB; MFMA_Q(4, 2); BARR;
  }
#undef STAGE_A
#undef STAGE_B
#undef DS_A
#undef DS_B
#undef MFMA_Q

  // epilogue: C/D layout col = lane&15, row = (lane>>4)*4 + j  (m89/m91)
  const int r0 = brow + wm * 128 + (lane >> 4) * 4;
  const int c0e = bcol + wn * 64 + lr;
  #pragma unroll
  for (int m = 0; m < 8; ++m) {
    const int row = r0 + m * 16;
    float xr[4];
    #pragma unroll
    for (int j = 0; j < 4; ++j) xr[j] = x2[row + j];
    #pragma unroll
    for (int n = 0; n < 4; ++n) {
      const int col = c0e + n * 16;
      if (col < N_DIM) {
        const float w2c = w2[col];
        #pragma unroll
        for (int j = 0; j < 4; ++j)
          out[(size_t)(row + j) * N_DIM + col] =
              (2.0f * acc[m][n][j] - xr[j] - w2c) * INV_F;
      }
    }
  }
}

// ---------------------------------------------------------------------------
// Safety net if ws_size is too small: direct fp32 computation.
// ---------------------------------------------------------------------------
__global__ __launch_bounds__(256) void fallback_fp32(
    const float* __restrict__ x, const float* __restrict__ w,
    float* __restrict__ out)
{
  long idx = (long)blockIdx.x * 256 + threadIdx.x;
  if (idx >= (long)M_DIM * N_DIM) return;
  int row = (int)(idx / N_DIM);
  int col = (int)(idx % N_DIM);
  const float4* xr = (const float4*)(x + (size_t)row * K_DIM);
  const float4* wr = (const float4*)(w + (size_t)col * K_DIM);
  float s = 0.f;
  for (int i = 0; i < K_DIM / 4; ++i) {
    float4 a = xr[i], b = wr[i];
    float d0 = a.x - b.x, d1 = a.y - b.y, d2 = a.z - b.z, d3 = a.w - b.w;
    s += d0*d0 + d1*d1 + d2*d2 + d3*d3;
  }
  out[idx] = -s * INV_F;
}

extern "C" void kernel_launch(void* const* d_in, const int* in_sizes, int n_in,
                              void* d_out, int out_size, void* d_ws, size_t ws_size,
                              hipStream_t stream) {
  const float* x = (const float*)d_in[0];
  const float* w = (const float*)d_in[1];
  float* out = (float*)d_out;

  const size_t need = (size_t)M_DIM * K_DIM * 2
                    + (size_t)N_PAD * K_DIM * 2
                    + (size_t)M_DIM * 4
                    + (size_t)N_PAD * 4;
  if (ws_size < need) {
    const long total = (long)M_DIM * N_DIM;
    fallback_fp32<<<(int)((total + 255) / 256), 256, 0, stream>>>(x, w, out);
    return;
  }

  __bf16* xb = (__bf16*)d_ws;
  __bf16* wb = xb + (size_t)M_DIM * K_DIM;
  float* x2 = (float*)(wb + (size_t)N_PAD * K_DIM);
  float* w2 = x2 + M_DIM;

  cvt_rows<<<M_DIM / 4, 256, 0, stream>>>(x, xb, x2, M_DIM);
  cvt_rows<<<N_PAD / 4, 256, 0, stream>>>(w, wb, w2, N_DIM);
  gemm_ep<<<(M_DIM / BM) * (N_PAD / BN), 512, 0, stream>>>(xb, wb, x2, w2, out);
}